// Round 2
// 154.737 us; speedup vs baseline: 1.1242x; 1.1242x over previous
//
#include <hip/hip_runtime.h>
#include <cmath>

// CrossAttention: B=4, N=4096, M=1024, QD=320, CD=768, ID=512, H=8, Dh=64
// fp32 I/O; bf16 MFMA internals, fp32 accumulate.
// r10: flash rewrite — key-row-permuted sK staging (kappa) makes exp2(S^T)
// registers directly form the K=32 PV B-fragment: P never touches LDS.
// l via f32 psum + epilogue shfl_xor (off the MFMA pipe). EK2F folded into
// MFMA C-operand (no per-tile C-init movs). LDS 69632 -> 40960 B.
// r11: identical resubmit (r10 bench died on container infra, no signal).
constexpr int BATCH  = 4;
constexpr int SEQ_N  = 4096;
constexpr int SEQ_M  = 1024;
constexpr int QD     = 320;
constexpr int CD     = 768;
constexpr int ID     = 512;
constexpr float QFOLD = 0.125f * 1.44269504f;   // SCALE*log2e folded into Wq
constexpr float EK2F  = -8.0f * 1.44269504f;    // fixed softmax shift (log2 dom)

typedef __bf16 bf16x8 __attribute__((ext_vector_type(8)));
typedef __bf16 bf16x4 __attribute__((ext_vector_type(4)));
typedef __bf16 bf16x2 __attribute__((ext_vector_type(2)));
typedef float  f32x4  __attribute__((ext_vector_type(4)));

__device__ __forceinline__ void gload_lds16(const __bf16* g, __bf16* l) {
    __builtin_amdgcn_global_load_lds(
        (const __attribute__((address_space(1))) void*)g,
        (__attribute__((address_space(3))) void*)l, 16, 0, 0);
}

__device__ __forceinline__ float fast_exp2(float x) {
#if __has_builtin(__builtin_amdgcn_exp2f)
    return __builtin_amdgcn_exp2f(x);
#else
    return exp2f(x);
#endif
}

// ---------------------------------------------------------------------------
// One dispatch: fp32->bf16 for x/ctx (blocks 0..4095) + weight transpose/cvt
// (blocks 4096..5183).  Wq pre-scaled by QFOLD.
// ---------------------------------------------------------------------------
__global__ __launch_bounds__(256)
void cvt_all(const float* __restrict__ x, const float* __restrict__ ctx,
             const float* __restrict__ Wq, const float* __restrict__ Wk,
             const float* __restrict__ Wv, const float* __restrict__ Wo,
             __bf16* __restrict__ xb, __bf16* __restrict__ ctxb,
             __bf16* __restrict__ WqT, __bf16* __restrict__ WkT,
             __bf16* __restrict__ WvT, __bf16* __restrict__ WoT) {
    __shared__ float tile[32][33];
    int bid = blockIdx.x;
    if (bid < 4096) {
        constexpr int NX8 = SEQ_N * BATCH * QD / 8;   // 655360
        int i = bid * 256 + threadIdx.x;
        const float* s; __bf16* d; int j;
        if (i < NX8) { s = x; d = xb; j = i; }
        else         { s = ctx; d = ctxb; j = i - NX8; }
        const float4* sp = reinterpret_cast<const float4*>(s) + (size_t)j * 2;
        float4 a = sp[0], b = sp[1];
        bf16x8 o = { (__bf16)a.x, (__bf16)a.y, (__bf16)a.z, (__bf16)a.w,
                     (__bf16)b.x, (__bf16)b.y, (__bf16)b.z, (__bf16)b.w };
        reinterpret_cast<bf16x8*>(d)[j] = o;
        return;
    }
    int wb = bid - 4096;
    const float* W; __bf16* WT; int K, N, tid; float scl = 1.0f;
    if (wb < 160)      { W = Wq; WT = WqT; K = 320; N = 512; tid = wb; scl = QFOLD; }
    else if (wb < 544) { W = Wk; WT = WkT; K = 768; N = 512; tid = wb - 160; }
    else if (wb < 928) { W = Wv; WT = WvT; K = 768; N = 512; tid = wb - 544; }
    else               { W = Wo; WT = WoT; K = 512; N = 320; tid = wb - 928; }
    int kt = K / 32;
    int k0 = (tid % kt) * 32, n0 = (tid / kt) * 32;
    int tc = threadIdx.x & 31, tr = threadIdx.x >> 5;
#pragma unroll
    for (int p = 0; p < 4; ++p)
        tile[p * 8 + tr][tc] = W[(size_t)(k0 + p * 8 + tr) * N + n0 + tc];
    __syncthreads();
#pragma unroll
    for (int p = 0; p < 4; ++p)
        WT[(size_t)(n0 + p * 8 + tr) * K + k0 + tc] = (__bf16)(tile[tc][p * 8 + tr] * scl);
}

// ---------------------------------------------------------------------------
// KV projection (r7/r8-verified): C = ctxb @ [WkT|WvT]^T.  64x64 tiles,
// BK=64 dbuf, XOR chunk swizzle, operand-swapped MFMA -> packed stores.
// blockIdx.y<8 -> Kb row-major; >=8 -> Vt (b,h,d,m) via LDS transpose.
// ---------------------------------------------------------------------------
__global__ __launch_bounds__(256)
void gemm_kv(const __bf16* __restrict__ A, const __bf16* __restrict__ BT,
             __bf16* __restrict__ Kb, __bf16* __restrict__ Vt, int M, int K) {
    __shared__ __attribute__((aligned(16))) __bf16 sA[2][64][64];
    __shared__ __attribute__((aligned(16))) __bf16 sB[2][64][64];

    const int t = threadIdx.x;
    const int wave = t >> 6, lane = t & 63;
    const int q = lane >> 4, c = lane & 15;
    const int wm = wave >> 1, wn = wave & 1;
    const int row0 = blockIdx.x * 64, col0 = blockIdx.y * 64;
    const int srow = lane >> 3, sch = lane & 7;
    const int fch = sch ^ srow;

    auto stage = [&](int buf, int k0) {
#pragma unroll
        for (int i = 0; i < 2; ++i) {
            int r = wave * 16 + i * 8;
            gload_lds16(A + (size_t)(row0 + r + srow) * K + k0 + fch * 8,
                        &sA[buf][r][0] + lane * 8);
            gload_lds16(BT + (size_t)(col0 + r + srow) * K + k0 + fch * 8,
                        &sB[buf][r][0] + lane * 8);
        }
    };

    f32x4 acc[2][2] = {};
    stage(0, 0);
    const int iters = K >> 6;
    for (int it = 0; it < iters; ++it) {
        const int p = it & 1;
        __syncthreads();
        if (it + 1 < iters) stage(p ^ 1, (it + 1) * 64);
#pragma unroll
        for (int ks = 0; ks < 2; ++ks) {
            const int so = ((ks * 4 + q) ^ (c & 7)) * 8;
            bf16x8 am[2], bn[2];
#pragma unroll
            for (int i = 0; i < 2; ++i)
                am[i] = *reinterpret_cast<const bf16x8*>(&sA[p][wm * 32 + i * 16 + c][0] + so);
#pragma unroll
            for (int j = 0; j < 2; ++j)
                bn[j] = *reinterpret_cast<const bf16x8*>(&sB[p][wn * 32 + j * 16 + c][0] + so);
#pragma unroll
            for (int i = 0; i < 2; ++i)
#pragma unroll
                for (int j = 0; j < 2; ++j)
                    acc[i][j] = __builtin_amdgcn_mfma_f32_16x16x32_bf16(bn[j], am[i], acc[i][j], 0, 0, 0);
        }
    }

    if (blockIdx.y < 8) {
#pragma unroll
        for (int i = 0; i < 2; ++i)
#pragma unroll
            for (int j = 0; j < 2; ++j) {
                int mrow = row0 + wm * 32 + i * 16 + c;
                int ncol = col0 + wn * 32 + j * 16 + q * 4;
                bf16x4 v = { (__bf16)acc[i][j][0], (__bf16)acc[i][j][1],
                             (__bf16)acc[i][j][2], (__bf16)acc[i][j][3] };
                *reinterpret_cast<bf16x4*>(&Kb[(size_t)mrow * 512 + ncol]) = v;
            }
    } else {
        __bf16* ldsT = (__bf16*)sA;   // 64 x 72
        __syncthreads();
#pragma unroll
        for (int i = 0; i < 2; ++i)
#pragma unroll
            for (int j = 0; j < 2; ++j) {
                int ml = wm * 32 + i * 16 + c;
                int dl = wn * 32 + j * 16 + q * 4;
#pragma unroll
                for (int r = 0; r < 4; ++r)
                    ldsT[(dl + r) * 72 + ml] = (__bf16)acc[i][j][r];
            }
        __syncthreads();
        int b = row0 >> 10, m0 = row0 & 1023;
        int h = (col0 - 512) >> 6;
        int d = t >> 2, ch = t & 3;
        __bf16* dst = Vt + (((size_t)((b * 8 + h) * 64 + d)) << 10) + m0 + ch * 16;
        const __bf16* src = &ldsT[d * 72 + ch * 16];
        *reinterpret_cast<bf16x8*>(dst)     = *reinterpret_cast<const bf16x8*>(src);
        *reinterpret_cast<bf16x8*>(dst + 8) = *reinterpret_cast<const bf16x8*>(src + 8);
    }
}

// ---------------------------------------------------------------------------
// Flash attention, fused Q-projection.  Block = (b,h) x 256 queries; 4 waves
// x 64 queries.  64-key tiles, double-buffered sK/sV (1 barrier/tile).
//
// Key-row permutation kappa (applied to sK STAGING only): within each 32-key
// group, LDS row rho holds key (rho&32)|8*((rho&15)>>2)|(rho&3)|4*((rho>>4)&1).
// Consequence: S^T = K*Q^T C-regs at lane (c,q): s[qt][2g]   = keys g*32+q*8+{0..3}
//                                               s[qt][2g+1] = keys g*32+q*8+{4..7}
// so exp2 of two adjacent ct-blocks concatenates into the exact 16x16x32
// B-fragment for O^T += V^T * P^T  ->  P stays in registers (no sPT, no
// bank conflicts, PV at full K=32 rate).  l = f32 psum + epilogue shfl_xor.
// LDS: max(prologue 20480, sQw 18432, KV dbuf 16384) elems = 40960 B.
// ---------------------------------------------------------------------------
__global__ __launch_bounds__(256, 2)
void flash_attn(const __bf16* __restrict__ xb, const __bf16* __restrict__ WqT,
                const __bf16* __restrict__ Kb, const __bf16* __restrict__ Vt,
                __bf16* __restrict__ AO) {
    __shared__ __attribute__((aligned(16))) __bf16 smem[20480];
    // prologue: sX=smem (256x64), sW=smem+16384 (64x64)
    // sQw = smem + wave*4608 (64x72, per-wave; consumed before first stageKV)
    // main: sK(buf)=smem+buf*8192, sV(buf)=smem+buf*8192+4096

    const int t = threadIdx.x;
    const int wave = t >> 6, lane = t & 63;
    const int q = lane >> 4, c = lane & 15;
    const int bh = blockIdx.y;
    const int b = bh >> 3, h = bh & 7;
    const int n0 = blockIdx.x * 256;
    const int srow = lane >> 3, sch = lane & 7;
    const int fch = sch ^ srow;

    // ---- Prologue: Q^T[64 d][256 q] = WqT_h @ xb^T, 5 staged BK=64 iters --
    f32x4 accQ[4][4] = {};   // [dt][qt]
    {
        __bf16* sX = smem;
        __bf16* sW = smem + 16384;
        for (int k0 = 0; k0 < QD; k0 += 64) {
            __syncthreads();
#pragma unroll
            for (int i = 0; i < 8; ++i) {
                int r = wave * 64 + i * 8;
                gload_lds16(xb + (size_t)(b * SEQ_N + n0 + r + srow) * QD + k0 + fch * 8,
                            sX + r * 64 + lane * 8);
            }
#pragma unroll
            for (int i = 0; i < 2; ++i) {
                int r = wave * 16 + i * 8;
                gload_lds16(WqT + (size_t)(h * 64 + r + srow) * QD + k0 + fch * 8,
                            sW + r * 64 + lane * 8);
            }
            __syncthreads();
#pragma unroll
            for (int ks = 0; ks < 2; ++ks) {
                const int so = ((ks * 4 + q) ^ (c & 7)) * 8;
                bf16x8 aw[4], bx[4];
#pragma unroll
                for (int dt = 0; dt < 4; ++dt)
                    aw[dt] = *reinterpret_cast<const bf16x8*>(sW + (dt * 16 + c) * 64 + so);
#pragma unroll
                for (int qt = 0; qt < 4; ++qt)
                    bx[qt] = *reinterpret_cast<const bf16x8*>(sX + (wave * 64 + qt * 16 + c) * 64 + so);
#pragma unroll
                for (int dt = 0; dt < 4; ++dt)
#pragma unroll
                    for (int qt = 0; qt < 4; ++qt)
                        accQ[dt][qt] = __builtin_amdgcn_mfma_f32_16x16x32_bf16(aw[dt], bx[qt], accQ[dt][qt], 0, 0, 0);
            }
        }
    }
    __syncthreads();   // all prologue LDS reads consumed before region reuse

    // C-layout -> per-wave LDS slice -> B-layout register frags (Q[query][d])
    __bf16* sQw = smem + wave * 4608;    // [64][72]
#pragma unroll
    for (int dt = 0; dt < 4; ++dt)
#pragma unroll
        for (int qt = 0; qt < 4; ++qt) {
            bf16x2 w0 = { (__bf16)accQ[dt][qt][0], (__bf16)accQ[dt][qt][1] };
            bf16x2 w1 = { (__bf16)accQ[dt][qt][2], (__bf16)accQ[dt][qt][3] };
            __bf16* pr = sQw + (qt * 16 + c) * 72 + dt * 16 + q * 4;
            *reinterpret_cast<bf16x2*>(pr)     = w0;
            *reinterpret_cast<bf16x2*>(pr + 2) = w1;
        }
    bf16x8 aq[4][2];
#pragma unroll
    for (int qt = 0; qt < 4; ++qt)
#pragma unroll
        for (int ks = 0; ks < 2; ++ks)
            aq[qt][ks] = *reinterpret_cast<const bf16x8*>(sQw + (qt * 16 + c) * 72 + ks * 32 + q * 8);
    __syncthreads();   // sQw reads done before KV staging overwrites region

    // ---- Main loop: dbuf KV, one barrier per tile -------------------------
    auto stageKV = [&](int buf, int m0) {
        __bf16* sK = smem + buf * 8192;
        __bf16* sV = smem + buf * 8192 + 4096;
#pragma unroll
        for (int i = 0; i < 2; ++i) {
            int r = wave * 16 + i * 8;
            int rho = r + srow;                                   // 0..63
            int kl = (rho & 32) | (((rho & 15) >> 2) << 3)
                   | (rho & 3) | (((rho >> 4) & 1) << 2);          // kappa(rho)
            gload_lds16(Kb + (size_t)(b * SEQ_M + m0 + kl) * ID + h * 64 + fch * 8,
                        sK + r * 64 + lane * 8);
            gload_lds16(Vt + (((size_t)((b * 8 + h) * 64 + rho)) << 10) + m0 + fch * 8,
                        sV + r * 64 + lane * 8);
        }
    };

    const f32x4 ekc = { EK2F, EK2F, EK2F, EK2F };
    f32x4 accO[4][4] = {};   // [qt][nt]
    float psum[4] = {};      // [qt] f32 row-sum partials (this lane's keys)

    stageKV(0, 0);
    constexpr int TILES = SEQ_M / 64;   // 16
    for (int mt = 0; mt < TILES; ++mt) {
        const int p = mt & 1;
        __syncthreads();                 // buf p staged (barrier drains vmcnt)
        if (mt + 1 < TILES) stageKV(p ^ 1, (mt + 1) * 64);
        const __bf16* sK = smem + p * 8192;
        const __bf16* sV = smem + p * 8192 + 4096;

        // S^T = K * Q^T + EK2F (shift enters as the first MFMA's C operand)
        f32x4 s[4][4];
#pragma unroll
        for (int ks = 0; ks < 2; ++ks) {
            const int so = ((ks * 4 + q) ^ (c & 7)) * 8;
#pragma unroll
            for (int ct = 0; ct < 4; ++ct) {
                bf16x8 ak = *reinterpret_cast<const bf16x8*>(sK + (ct * 16 + c) * 64 + so);
#pragma unroll
                for (int qt = 0; qt < 4; ++qt)
                    s[qt][ct] = (ks == 0)
                        ? __builtin_amdgcn_mfma_f32_16x16x32_bf16(ak, aq[qt][0], ekc, 0, 0, 0)
                        : __builtin_amdgcn_mfma_f32_16x16x32_bf16(ak, aq[qt][1], s[qt][ct], 0, 0, 0);
            }
        }

        // p = exp2(s): kappa makes {s[qt][2g], s[qt][2g+1]} = keys g*32+q*8+{0..7}
        // -> bp[qt][g] is the PV B-fragment directly (no LDS round-trip).
        bf16x8 bp[4][2];
#pragma unroll
        for (int qt = 0; qt < 4; ++qt) {
            float pp[16];
#pragma unroll
            for (int ct = 0; ct < 4; ++ct)
#pragma unroll
                for (int r = 0; r < 4; ++r)
                    pp[ct * 4 + r] = fast_exp2(s[qt][ct][r]);
#pragma unroll
            for (int g = 0; g < 2; ++g)
                bp[qt][g] = bf16x8{ (__bf16)pp[g * 8 + 0], (__bf16)pp[g * 8 + 1],
                                    (__bf16)pp[g * 8 + 2], (__bf16)pp[g * 8 + 3],
                                    (__bf16)pp[g * 8 + 4], (__bf16)pp[g * 8 + 5],
                                    (__bf16)pp[g * 8 + 6], (__bf16)pp[g * 8 + 7] };
            psum[qt] += (((pp[0] + pp[1]) + (pp[2] + pp[3])) +
                         ((pp[4] + pp[5]) + (pp[6] + pp[7]))) +
                        (((pp[8] + pp[9]) + (pp[10] + pp[11])) +
                         ((pp[12] + pp[13]) + (pp[14] + pp[15])));
        }

        // O^T += V^T * P^T  (full-rate K=32, B from registers)
#pragma unroll
        for (int ks = 0; ks < 2; ++ks) {
            const int so = ((ks * 4 + q) ^ (c & 7)) * 8;
#pragma unroll
            for (int nt = 0; nt < 4; ++nt) {
                bf16x8 av = *reinterpret_cast<const bf16x8*>(sV + (nt * 16 + c) * 64 + so);
#pragma unroll
                for (int qt = 0; qt < 4; ++qt)
                    accO[qt][nt] = __builtin_amdgcn_mfma_f32_16x16x32_bf16(av, bp[qt][ks], accO[qt][nt], 0, 0, 0);
            }
        }
    }

    // epilogue: l = cross-lane sum over the 4 q-groups; O /= l; packed stores
#pragma unroll
    for (int qt = 0; qt < 4; ++qt) {
        float l = psum[qt];
        l += __shfl_xor(l, 16);
        l += __shfl_xor(l, 32);
        float inv = 1.0f / l;
        size_t rowb = (size_t)(b * SEQ_N + n0 + wave * 64 + qt * 16 + c) * ID + h * 64;
#pragma unroll
        for (int nt = 0; nt < 4; ++nt) {
            bf16x4 v = { (__bf16)(accO[qt][nt][0] * inv), (__bf16)(accO[qt][nt][1] * inv),
                         (__bf16)(accO[qt][nt][2] * inv), (__bf16)(accO[qt][nt][3] * inv) };
            *reinterpret_cast<bf16x4*>(&AO[rowb + nt * 16 + q * 4]) = v;
        }
    }
}

// ---------------------------------------------------------------------------
// Output projection: out[16384 x 320] = AO @ WoT^T + bias, fp32 out.
// 128x64 tiles (grid 640 = 2.5/CU), wave tile 64x32 (16 MFMA/iter), BK=64
// dbuf (48 KB -> 3 blocks/CU), XOR swizzle, operand-swapped -> float4 stores.
// ---------------------------------------------------------------------------
__global__ __launch_bounds__(256)
void gemm_out(const __bf16* __restrict__ A, const __bf16* __restrict__ BT,
              const float* __restrict__ bias, float* __restrict__ C,
              int M, int N, int K) {
    __shared__ __attribute__((aligned(16))) __bf16 sA[2][128][64];
    __shared__ __attribute__((aligned(16))) __bf16 sB[2][64][64];

    const int t = threadIdx.x;
    const int wave = t >> 6, lane = t & 63;
    const int q = lane >> 4, c = lane & 15;
    const int wm = wave >> 1, wn = wave & 1;
    const int row0 = blockIdx.x * 128, col0 = blockIdx.y * 64;
    const int srow = lane >> 3, sch = lane & 7;
    const int fch = sch ^ srow;

    auto stage = [&](int buf, int k0) {
#pragma unroll
        for (int i = 0; i < 4; ++i) {
            int r = wave * 32 + i * 8;
            gload_lds16(A + (size_t)(row0 + r + srow) * K + k0 + fch * 8,
                        &sA[buf][r][0] + lane * 8);
        }
#pragma unroll
        for (int i = 0; i < 2; ++i) {
            int r = wave * 16 + i * 8;
            gload_lds16(BT + (size_t)(col0 + r + srow) * K + k0 + fch * 8,
                        &sB[buf][r][0] + lane * 8);
        }
    };

    f32x4 acc[4][2] = {};   // [i: m-sub (64 rows)][j: n-sub (32 cols)]
    stage(0, 0);
    const int iters = K >> 6;
    for (int it = 0; it < iters; ++it) {
        const int p = it & 1;
        __syncthreads();
        if (it + 1 < iters) stage(p ^ 1, (it + 1) * 64);
#pragma unroll
        for (int ks = 0; ks < 2; ++ks) {
            const int so = ((ks * 4 + q) ^ (c & 7)) * 8;
            bf16x8 am[4], bn[2];
#pragma unroll
            for (int i = 0; i < 4; ++i)
                am[i] = *reinterpret_cast<const bf16x8*>(&sA[p][wm * 64 + i * 16 + c][0] + so);
#pragma unroll
            for (int j = 0; j < 2; ++j)
                bn[j] = *reinterpret_cast<const bf16x8*>(&sB[p][wn * 32 + j * 16 + c][0] + so);
#pragma unroll
            for (int i = 0; i < 4; ++i)
#pragma unroll
                for (int j = 0; j < 2; ++j)
                    acc[i][j] = __builtin_amdgcn_mfma_f32_16x16x32_bf16(bn[j], am[i], acc[i][j], 0, 0, 0);
        }
    }

#pragma unroll
    for (int i = 0; i < 4; ++i)
#pragma unroll
        for (int j = 0; j < 2; ++j) {
            int mrow = row0 + wm * 64 + i * 16 + c;
            int ncol = col0 + wn * 32 + j * 16 + q * 4;
            float4 v = { acc[i][j][0] + bias[ncol + 0],
                         acc[i][j][1] + bias[ncol + 1],
                         acc[i][j][2] + bias[ncol + 2],
                         acc[i][j][3] + bias[ncol + 3] };
            *reinterpret_cast<float4*>(&C[(size_t)mrow * N + ncol]) = v;
        }
}

// ---------------------------------------------------------------------------
extern "C" void kernel_launch(void* const* d_in, const int* in_sizes, int n_in,
                              void* d_out, int out_size, void* d_ws, size_t ws_size,
                              hipStream_t stream) {
    const float* x   = (const float*)d_in[0];
    const float* ctx = (const float*)d_in[1];
    const float* Wq  = (const float*)d_in[2];
    const float* Wk  = (const float*)d_in[3];
    const float* Wv  = (const float*)d_in[4];
    const float* Wo  = (const float*)d_in[5];
    const float* bo  = (const float*)d_in[6];
    float* out = (float*)d_out;

    char* ws = (char*)d_ws;
    __bf16* xb   = (__bf16*)(ws + 0);                 // 16384x320 (stays live)
    __bf16* ctxb = (__bf16*)(ws + 10485760);          // 4096x768
    __bf16* AO   = (__bf16*)(ws + 16777216);          // 16384x512
    __bf16* Kb   = (__bf16*)(ws + 33554432);          // 4096x512
    __bf16* Vt   = (__bf16*)(ws + 37748736);          // (32,64,1024)
    __bf16* WqT  = (__bf16*)(ws + 41943040);          // 512x320 (pre-scaled)
    __bf16* WkT  = (__bf16*)(ws + 42270720);          // 512x768 \ adjacent
    __bf16* WvT  = (__bf16*)(ws + 43057152);          // 512x768 / = 1024x768
    __bf16* WoT  = (__bf16*)(ws + 43843584);          // 320x512

    const int MX = BATCH * SEQ_N;   // 16384
    const int MC = BATCH * SEQ_M;   // 4096
    dim3 blk(256);

    cvt_all<<<dim3(5184), blk, 0, stream>>>(x, ctx, Wq, Wk, Wv, Wo,
                                            xb, ctxb, WqT, WkT, WvT, WoT);

    // fused K+V projection (y<8 -> Kb, y>=8 -> Vt transposed)
    gemm_kv<<<dim3(MC / 64, 16), blk, 0, stream>>>(ctxb, WkT, Kb, Vt, MC, CD);

    // flash with fused Q-projection (256 queries/block)
    flash_attn<<<dim3(SEQ_N / 256, 32), blk, 0, stream>>>(xb, WqT, Kb, Vt, AO);

    // output projection + bias (fp32 out)
    gemm_out<<<dim3(MX / 128, QD / 64), blk, 0, stream>>>(AO, WoT, bo, out, MX, QD, ID);
}

// Round 3
// 154.303 us; speedup vs baseline: 1.1273x; 1.0028x over previous
//
#include <hip/hip_runtime.h>
#include <cmath>

// CrossAttention: B=4, N=4096, M=1024, QD=320, CD=768, ID=512, H=8, Dh=64
// fp32 I/O; bf16 MFMA internals, fp32 accumulate.
// r10/r11: kappa-permuted sK staging -> P stays in registers (no sPT).
// r12: flash -> 512-thread blocks (8 waves, 32 q/wave): 4 waves/SIMD
// (was 2) for latency hiding; s_setprio(1) around MFMA clusters (T5 —
// pays now that waves have role diversity). LDS/grid/traffic unchanged.
constexpr int BATCH  = 4;
constexpr int SEQ_N  = 4096;
constexpr int SEQ_M  = 1024;
constexpr int QD     = 320;
constexpr int CD     = 768;
constexpr int ID     = 512;
constexpr float QFOLD = 0.125f * 1.44269504f;   // SCALE*log2e folded into Wq
constexpr float EK2F  = -8.0f * 1.44269504f;    // fixed softmax shift (log2 dom)

typedef __bf16 bf16x8 __attribute__((ext_vector_type(8)));
typedef __bf16 bf16x4 __attribute__((ext_vector_type(4)));
typedef __bf16 bf16x2 __attribute__((ext_vector_type(2)));
typedef float  f32x4  __attribute__((ext_vector_type(4)));

__device__ __forceinline__ void gload_lds16(const __bf16* g, __bf16* l) {
    __builtin_amdgcn_global_load_lds(
        (const __attribute__((address_space(1))) void*)g,
        (__attribute__((address_space(3))) void*)l, 16, 0, 0);
}

__device__ __forceinline__ float fast_exp2(float x) {
#if __has_builtin(__builtin_amdgcn_exp2f)
    return __builtin_amdgcn_exp2f(x);
#else
    return exp2f(x);
#endif
}

// ---------------------------------------------------------------------------
// One dispatch: fp32->bf16 for x/ctx (blocks 0..4095) + weight transpose/cvt
// (blocks 4096..5183).  Wq pre-scaled by QFOLD.
// ---------------------------------------------------------------------------
__global__ __launch_bounds__(256)
void cvt_all(const float* __restrict__ x, const float* __restrict__ ctx,
             const float* __restrict__ Wq, const float* __restrict__ Wk,
             const float* __restrict__ Wv, const float* __restrict__ Wo,
             __bf16* __restrict__ xb, __bf16* __restrict__ ctxb,
             __bf16* __restrict__ WqT, __bf16* __restrict__ WkT,
             __bf16* __restrict__ WvT, __bf16* __restrict__ WoT) {
    __shared__ float tile[32][33];
    int bid = blockIdx.x;
    if (bid < 4096) {
        constexpr int NX8 = SEQ_N * BATCH * QD / 8;   // 655360
        int i = bid * 256 + threadIdx.x;
        const float* s; __bf16* d; int j;
        if (i < NX8) { s = x; d = xb; j = i; }
        else         { s = ctx; d = ctxb; j = i - NX8; }
        const float4* sp = reinterpret_cast<const float4*>(s) + (size_t)j * 2;
        float4 a = sp[0], b = sp[1];
        bf16x8 o = { (__bf16)a.x, (__bf16)a.y, (__bf16)a.z, (__bf16)a.w,
                     (__bf16)b.x, (__bf16)b.y, (__bf16)b.z, (__bf16)b.w };
        reinterpret_cast<bf16x8*>(d)[j] = o;
        return;
    }
    int wb = bid - 4096;
    const float* W; __bf16* WT; int K, N, tid; float scl = 1.0f;
    if (wb < 160)      { W = Wq; WT = WqT; K = 320; N = 512; tid = wb; scl = QFOLD; }
    else if (wb < 544) { W = Wk; WT = WkT; K = 768; N = 512; tid = wb - 160; }
    else if (wb < 928) { W = Wv; WT = WvT; K = 768; N = 512; tid = wb - 544; }
    else               { W = Wo; WT = WoT; K = 512; N = 320; tid = wb - 928; }
    int kt = K / 32;
    int k0 = (tid % kt) * 32, n0 = (tid / kt) * 32;
    int tc = threadIdx.x & 31, tr = threadIdx.x >> 5;
#pragma unroll
    for (int p = 0; p < 4; ++p)
        tile[p * 8 + tr][tc] = W[(size_t)(k0 + p * 8 + tr) * N + n0 + tc];
    __syncthreads();
#pragma unroll
    for (int p = 0; p < 4; ++p)
        WT[(size_t)(n0 + p * 8 + tr) * K + k0 + tc] = (__bf16)(tile[tc][p * 8 + tr] * scl);
}

// ---------------------------------------------------------------------------
// KV projection (r7/r8-verified): C = ctxb @ [WkT|WvT]^T.  64x64 tiles,
// BK=64 dbuf, XOR chunk swizzle, operand-swapped MFMA -> packed stores.
// blockIdx.y<8 -> Kb row-major; >=8 -> Vt (b,h,d,m) via LDS transpose.
// ---------------------------------------------------------------------------
__global__ __launch_bounds__(256)
void gemm_kv(const __bf16* __restrict__ A, const __bf16* __restrict__ BT,
             __bf16* __restrict__ Kb, __bf16* __restrict__ Vt, int M, int K) {
    __shared__ __attribute__((aligned(16))) __bf16 sA[2][64][64];
    __shared__ __attribute__((aligned(16))) __bf16 sB[2][64][64];

    const int t = threadIdx.x;
    const int wave = t >> 6, lane = t & 63;
    const int q = lane >> 4, c = lane & 15;
    const int wm = wave >> 1, wn = wave & 1;
    const int row0 = blockIdx.x * 64, col0 = blockIdx.y * 64;
    const int srow = lane >> 3, sch = lane & 7;
    const int fch = sch ^ srow;

    auto stage = [&](int buf, int k0) {
#pragma unroll
        for (int i = 0; i < 2; ++i) {
            int r = wave * 16 + i * 8;
            gload_lds16(A + (size_t)(row0 + r + srow) * K + k0 + fch * 8,
                        &sA[buf][r][0] + lane * 8);
            gload_lds16(BT + (size_t)(col0 + r + srow) * K + k0 + fch * 8,
                        &sB[buf][r][0] + lane * 8);
        }
    };

    f32x4 acc[2][2] = {};
    stage(0, 0);
    const int iters = K >> 6;
    for (int it = 0; it < iters; ++it) {
        const int p = it & 1;
        __syncthreads();
        if (it + 1 < iters) stage(p ^ 1, (it + 1) * 64);
#pragma unroll
        for (int ks = 0; ks < 2; ++ks) {
            const int so = ((ks * 4 + q) ^ (c & 7)) * 8;
            bf16x8 am[2], bn[2];
#pragma unroll
            for (int i = 0; i < 2; ++i)
                am[i] = *reinterpret_cast<const bf16x8*>(&sA[p][wm * 32 + i * 16 + c][0] + so);
#pragma unroll
            for (int j = 0; j < 2; ++j)
                bn[j] = *reinterpret_cast<const bf16x8*>(&sB[p][wn * 32 + j * 16 + c][0] + so);
#pragma unroll
            for (int i = 0; i < 2; ++i)
#pragma unroll
                for (int j = 0; j < 2; ++j)
                    acc[i][j] = __builtin_amdgcn_mfma_f32_16x16x32_bf16(bn[j], am[i], acc[i][j], 0, 0, 0);
        }
    }

    if (blockIdx.y < 8) {
#pragma unroll
        for (int i = 0; i < 2; ++i)
#pragma unroll
            for (int j = 0; j < 2; ++j) {
                int mrow = row0 + wm * 32 + i * 16 + c;
                int ncol = col0 + wn * 32 + j * 16 + q * 4;
                bf16x4 v = { (__bf16)acc[i][j][0], (__bf16)acc[i][j][1],
                             (__bf16)acc[i][j][2], (__bf16)acc[i][j][3] };
                *reinterpret_cast<bf16x4*>(&Kb[(size_t)mrow * 512 + ncol]) = v;
            }
    } else {
        __bf16* ldsT = (__bf16*)sA;   // 64 x 72
        __syncthreads();
#pragma unroll
        for (int i = 0; i < 2; ++i)
#pragma unroll
            for (int j = 0; j < 2; ++j) {
                int ml = wm * 32 + i * 16 + c;
                int dl = wn * 32 + j * 16 + q * 4;
#pragma unroll
                for (int r = 0; r < 4; ++r)
                    ldsT[(dl + r) * 72 + ml] = (__bf16)acc[i][j][r];
            }
        __syncthreads();
        int b = row0 >> 10, m0 = row0 & 1023;
        int h = (col0 - 512) >> 6;
        int d = t >> 2, ch = t & 3;
        __bf16* dst = Vt + (((size_t)((b * 8 + h) * 64 + d)) << 10) + m0 + ch * 16;
        const __bf16* src = &ldsT[d * 72 + ch * 16];
        *reinterpret_cast<bf16x8*>(dst)     = *reinterpret_cast<const bf16x8*>(src);
        *reinterpret_cast<bf16x8*>(dst + 8) = *reinterpret_cast<const bf16x8*>(src + 8);
    }
}

// ---------------------------------------------------------------------------
// Flash attention, fused Q-projection.  Block = (b,h) x 256 queries; 8 waves
// x 32 queries (qt=2).  64-key tiles, double-buffered sK/sV (1 barrier/tile).
//
// kappa (sK staging row permutation): LDS row rho holds key
// (rho&32)|8*((rho&15)>>2)|(rho&3)|4*((rho>>4)&1); then exp2 of two adjacent
// S^T ct-blocks concatenates into the exact 16x16x32 PV B-fragment -> P never
// touches LDS.  l = f32 psum + epilogue shfl_xor.  setprio(1) around MFMA
// clusters (waves at different phases -> scheduler favors MFMA-entering wave).
// LDS: max(prologue 20480, sQw 8x2304=18432, KV dbuf 16384) elems = 40960 B.
// ---------------------------------------------------------------------------
__global__ __launch_bounds__(512, 4)
void flash_attn(const __bf16* __restrict__ xb, const __bf16* __restrict__ WqT,
                const __bf16* __restrict__ Kb, const __bf16* __restrict__ Vt,
                __bf16* __restrict__ AO) {
    __shared__ __attribute__((aligned(16))) __bf16 smem[20480];
    // prologue: sX=smem (256x64), sW=smem+16384 (64x64)
    // sQw = smem + wave*2304 (32x72 per wave; consumed before first stageKV)
    // main: sK(buf)=smem+buf*8192, sV(buf)=smem+buf*8192+4096

    const int t = threadIdx.x;
    const int wave = t >> 6, lane = t & 63;
    const int q = lane >> 4, c = lane & 15;
    const int bh = blockIdx.y;
    const int b = bh >> 3, h = bh & 7;
    const int n0 = blockIdx.x * 256;
    const int srow = lane >> 3, sch = lane & 7;
    const int fch = sch ^ srow;

    // ---- Prologue: Q^T[64 d][256 q] = WqT_h @ xb^T, 5 staged BK=64 iters --
    f32x4 accQ[4][2] = {};   // [dt][qt]
    {
        __bf16* sX = smem;
        __bf16* sW = smem + 16384;
        for (int k0 = 0; k0 < QD; k0 += 64) {
            __syncthreads();
#pragma unroll
            for (int i = 0; i < 4; ++i) {
                int r = wave * 32 + i * 8;
                gload_lds16(xb + (size_t)(b * SEQ_N + n0 + r + srow) * QD + k0 + fch * 8,
                            sX + r * 64 + lane * 8);
            }
            {
                int r = wave * 8;
                gload_lds16(WqT + (size_t)(h * 64 + r + srow) * QD + k0 + fch * 8,
                            sW + r * 64 + lane * 8);
            }
            __syncthreads();
#pragma unroll
            for (int ks = 0; ks < 2; ++ks) {
                const int so = ((ks * 4 + q) ^ (c & 7)) * 8;
                bf16x8 aw[4], bx[2];
#pragma unroll
                for (int dt = 0; dt < 4; ++dt)
                    aw[dt] = *reinterpret_cast<const bf16x8*>(sW + (dt * 16 + c) * 64 + so);
#pragma unroll
                for (int qt = 0; qt < 2; ++qt)
                    bx[qt] = *reinterpret_cast<const bf16x8*>(sX + (wave * 32 + qt * 16 + c) * 64 + so);
#pragma unroll
                for (int dt = 0; dt < 4; ++dt)
#pragma unroll
                    for (int qt = 0; qt < 2; ++qt)
                        accQ[dt][qt] = __builtin_amdgcn_mfma_f32_16x16x32_bf16(aw[dt], bx[qt], accQ[dt][qt], 0, 0, 0);
            }
        }
    }
    __syncthreads();   // all prologue LDS reads consumed before region reuse

    // C-layout -> per-wave LDS slice -> B-layout register frags (Q[query][d])
    __bf16* sQw = smem + wave * 2304;    // [32][72]
#pragma unroll
    for (int dt = 0; dt < 4; ++dt)
#pragma unroll
        for (int qt = 0; qt < 2; ++qt) {
            bf16x2 w0 = { (__bf16)accQ[dt][qt][0], (__bf16)accQ[dt][qt][1] };
            bf16x2 w1 = { (__bf16)accQ[dt][qt][2], (__bf16)accQ[dt][qt][3] };
            __bf16* pr = sQw + (qt * 16 + c) * 72 + dt * 16 + q * 4;
            *reinterpret_cast<bf16x2*>(pr)     = w0;
            *reinterpret_cast<bf16x2*>(pr + 2) = w1;
        }
    bf16x8 aq[2][2];
#pragma unroll
    for (int qt = 0; qt < 2; ++qt)
#pragma unroll
        for (int ks = 0; ks < 2; ++ks)
            aq[qt][ks] = *reinterpret_cast<const bf16x8*>(sQw + (qt * 16 + c) * 72 + ks * 32 + q * 8);
    __syncthreads();   // sQw reads done before KV staging overwrites region

    // ---- Main loop: dbuf KV, one barrier per tile -------------------------
    auto stageKV = [&](int buf, int m0) {
        __bf16* sK = smem + buf * 8192;
        __bf16* sV = smem + buf * 8192 + 4096;
        int r = wave * 8;
        int rho = r + srow;                                   // 0..63
        int kl = (rho & 32) | (((rho & 15) >> 2) << 3)
               | (rho & 3) | (((rho >> 4) & 1) << 2);          // kappa(rho)
        gload_lds16(Kb + (size_t)(b * SEQ_M + m0 + kl) * ID + h * 64 + fch * 8,
                    sK + r * 64 + lane * 8);
        gload_lds16(Vt + (((size_t)((b * 8 + h) * 64 + rho)) << 10) + m0 + fch * 8,
                    sV + r * 64 + lane * 8);
    };

    const f32x4 ekc = { EK2F, EK2F, EK2F, EK2F };
    f32x4 accO[2][4] = {};   // [qt][nt]
    float psum[2] = {};      // [qt] f32 row-sum partials (this lane's keys)

    stageKV(0, 0);
    constexpr int TILES = SEQ_M / 64;   // 16
    for (int mt = 0; mt < TILES; ++mt) {
        const int p = mt & 1;
        __syncthreads();                 // buf p staged (barrier drains vmcnt)
        if (mt + 1 < TILES) stageKV(p ^ 1, (mt + 1) * 64);
        const __bf16* sK = smem + p * 8192;
        const __bf16* sV = smem + p * 8192 + 4096;

        // S^T = K * Q^T + EK2F (shift enters as the first MFMA's C operand)
        f32x4 s[2][4];
        __builtin_amdgcn_s_setprio(1);
#pragma unroll
        for (int ks = 0; ks < 2; ++ks) {
            const int so = ((ks * 4 + q) ^ (c & 7)) * 8;
#pragma unroll
            for (int ct = 0; ct < 4; ++ct) {
                bf16x8 ak = *reinterpret_cast<const bf16x8*>(sK + (ct * 16 + c) * 64 + so);
#pragma unroll
                for (int qt = 0; qt < 2; ++qt)
                    s[qt][ct] = (ks == 0)
                        ? __builtin_amdgcn_mfma_f32_16x16x32_bf16(ak, aq[qt][0], ekc, 0, 0, 0)
                        : __builtin_amdgcn_mfma_f32_16x16x32_bf16(ak, aq[qt][1], s[qt][ct], 0, 0, 0);
            }
        }
        __builtin_amdgcn_s_setprio(0);

        // p = exp2(s): kappa makes {s[qt][2g], s[qt][2g+1]} = keys g*32+q*8+{0..7}
        // -> bp[qt][g] is the PV B-fragment directly (no LDS round-trip).
        bf16x8 bp[2][2];
#pragma unroll
        for (int qt = 0; qt < 2; ++qt) {
            float pp[16];
#pragma unroll
            for (int ct = 0; ct < 4; ++ct)
#pragma unroll
                for (int r = 0; r < 4; ++r)
                    pp[ct * 4 + r] = fast_exp2(s[qt][ct][r]);
#pragma unroll
            for (int g = 0; g < 2; ++g)
                bp[qt][g] = bf16x8{ (__bf16)pp[g * 8 + 0], (__bf16)pp[g * 8 + 1],
                                    (__bf16)pp[g * 8 + 2], (__bf16)pp[g * 8 + 3],
                                    (__bf16)pp[g * 8 + 4], (__bf16)pp[g * 8 + 5],
                                    (__bf16)pp[g * 8 + 6], (__bf16)pp[g * 8 + 7] };
            psum[qt] += (((pp[0] + pp[1]) + (pp[2] + pp[3])) +
                         ((pp[4] + pp[5]) + (pp[6] + pp[7]))) +
                        (((pp[8] + pp[9]) + (pp[10] + pp[11])) +
                         ((pp[12] + pp[13]) + (pp[14] + pp[15])));
        }

        // O^T += V^T * P^T  (full-rate K=32, B from registers)
        __builtin_amdgcn_s_setprio(1);
#pragma unroll
        for (int ks = 0; ks < 2; ++ks) {
            const int so = ((ks * 4 + q) ^ (c & 7)) * 8;
#pragma unroll
            for (int nt = 0; nt < 4; ++nt) {
                bf16x8 av = *reinterpret_cast<const bf16x8*>(sV + (nt * 16 + c) * 64 + so);
#pragma unroll
                for (int qt = 0; qt < 2; ++qt)
                    accO[qt][nt] = __builtin_amdgcn_mfma_f32_16x16x32_bf16(av, bp[qt][ks], accO[qt][nt], 0, 0, 0);
            }
        }
        __builtin_amdgcn_s_setprio(0);
    }

    // epilogue: l = cross-lane sum over the 4 q-groups; O /= l; packed stores
#pragma unroll
    for (int qt = 0; qt < 2; ++qt) {
        float l = psum[qt];
        l += __shfl_xor(l, 16);
        l += __shfl_xor(l, 32);
        float inv = 1.0f / l;
        size_t rowb = (size_t)(b * SEQ_N + n0 + wave * 32 + qt * 16 + c) * ID + h * 64;
#pragma unroll
        for (int nt = 0; nt < 4; ++nt) {
            bf16x4 v = { (__bf16)(accO[qt][nt][0] * inv), (__bf16)(accO[qt][nt][1] * inv),
                         (__bf16)(accO[qt][nt][2] * inv), (__bf16)(accO[qt][nt][3] * inv) };
            *reinterpret_cast<bf16x4*>(&AO[rowb + nt * 16 + q * 4]) = v;
        }
    }
}

// ---------------------------------------------------------------------------
// Output projection: out[16384 x 320] = AO @ WoT^T + bias, fp32 out.
// 128x64 tiles (grid 640 = 2.5/CU), wave tile 64x32 (16 MFMA/iter), BK=64
// dbuf (48 KB -> 3 blocks/CU), XOR swizzle, operand-swapped -> float4 stores.
// ---------------------------------------------------------------------------
__global__ __launch_bounds__(256)
void gemm_out(const __bf16* __restrict__ A, const __bf16* __restrict__ BT,
              const float* __restrict__ bias, float* __restrict__ C,
              int M, int N, int K) {
    __shared__ __attribute__((aligned(16))) __bf16 sA[2][128][64];
    __shared__ __attribute__((aligned(16))) __bf16 sB[2][64][64];

    const int t = threadIdx.x;
    const int wave = t >> 6, lane = t & 63;
    const int q = lane >> 4, c = lane & 15;
    const int wm = wave >> 1, wn = wave & 1;
    const int row0 = blockIdx.x * 128, col0 = blockIdx.y * 64;
    const int srow = lane >> 3, sch = lane & 7;
    const int fch = sch ^ srow;

    auto stage = [&](int buf, int k0) {
#pragma unroll
        for (int i = 0; i < 4; ++i) {
            int r = wave * 32 + i * 8;
            gload_lds16(A + (size_t)(row0 + r + srow) * K + k0 + fch * 8,
                        &sA[buf][r][0] + lane * 8);
        }
#pragma unroll
        for (int i = 0; i < 2; ++i) {
            int r = wave * 16 + i * 8;
            gload_lds16(BT + (size_t)(col0 + r + srow) * K + k0 + fch * 8,
                        &sB[buf][r][0] + lane * 8);
        }
    };

    f32x4 acc[4][2] = {};   // [i: m-sub (64 rows)][j: n-sub (32 cols)]
    stage(0, 0);
    const int iters = K >> 6;
    for (int it = 0; it < iters; ++it) {
        const int p = it & 1;
        __syncthreads();
        if (it + 1 < iters) stage(p ^ 1, (it + 1) * 64);
#pragma unroll
        for (int ks = 0; ks < 2; ++ks) {
            const int so = ((ks * 4 + q) ^ (c & 7)) * 8;
            bf16x8 am[4], bn[2];
#pragma unroll
            for (int i = 0; i < 4; ++i)
                am[i] = *reinterpret_cast<const bf16x8*>(&sA[p][wm * 64 + i * 16 + c][0] + so);
#pragma unroll
            for (int j = 0; j < 2; ++j)
                bn[j] = *reinterpret_cast<const bf16x8*>(&sB[p][wn * 32 + j * 16 + c][0] + so);
#pragma unroll
            for (int i = 0; i < 4; ++i)
#pragma unroll
                for (int j = 0; j < 2; ++j)
                    acc[i][j] = __builtin_amdgcn_mfma_f32_16x16x32_bf16(bn[j], am[i], acc[i][j], 0, 0, 0);
        }
    }

#pragma unroll
    for (int i = 0; i < 4; ++i)
#pragma unroll
        for (int j = 0; j < 2; ++j) {
            int mrow = row0 + wm * 64 + i * 16 + c;
            int ncol = col0 + wn * 32 + j * 16 + q * 4;
            float4 v = { acc[i][j][0] + bias[ncol + 0],
                         acc[i][j][1] + bias[ncol + 1],
                         acc[i][j][2] + bias[ncol + 2],
                         acc[i][j][3] + bias[ncol + 3] };
            *reinterpret_cast<float4*>(&C[(size_t)mrow * N + ncol]) = v;
        }
}

// ---------------------------------------------------------------------------
extern "C" void kernel_launch(void* const* d_in, const int* in_sizes, int n_in,
                              void* d_out, int out_size, void* d_ws, size_t ws_size,
                              hipStream_t stream) {
    const float* x   = (const float*)d_in[0];
    const float* ctx = (const float*)d_in[1];
    const float* Wq  = (const float*)d_in[2];
    const float* Wk  = (const float*)d_in[3];
    const float* Wv  = (const float*)d_in[4];
    const float* Wo  = (const float*)d_in[5];
    const float* bo  = (const float*)d_in[6];
    float* out = (float*)d_out;

    char* ws = (char*)d_ws;
    __bf16* xb   = (__bf16*)(ws + 0);                 // 16384x320 (stays live)
    __bf16* ctxb = (__bf16*)(ws + 10485760);          // 4096x768
    __bf16* AO   = (__bf16*)(ws + 16777216);          // 16384x512
    __bf16* Kb   = (__bf16*)(ws + 33554432);          // 4096x512
    __bf16* Vt   = (__bf16*)(ws + 37748736);          // (32,64,1024)
    __bf16* WqT  = (__bf16*)(ws + 41943040);          // 512x320 (pre-scaled)
    __bf16* WkT  = (__bf16*)(ws + 42270720);          // 512x768 \ adjacent
    __bf16* WvT  = (__bf16*)(ws + 43057152);          // 512x768 / = 1024x768
    __bf16* WoT  = (__bf16*)(ws + 43843584);          // 320x512

    const int MX = BATCH * SEQ_N;   // 16384
    const int MC = BATCH * SEQ_M;   // 4096
    dim3 blk(256);

    cvt_all<<<dim3(5184), blk, 0, stream>>>(x, ctx, Wq, Wk, Wv, Wo,
                                            xb, ctxb, WqT, WkT, WvT, WoT);

    // fused K+V projection (y<8 -> Kb, y>=8 -> Vt transposed)
    gemm_kv<<<dim3(MC / 64, 16), blk, 0, stream>>>(ctxb, WkT, Kb, Vt, MC, CD);

    // flash with fused Q-projection (256 queries/block, 8 waves)
    flash_attn<<<dim3(SEQ_N / 256, 32), dim3(512), 0, stream>>>(xb, WqT, Kb, Vt, AO);

    // output projection + bias (fp32 out)
    gemm_out<<<dim3(MX / 128, QD / 64), blk, 0, stream>>>(AO, WoT, bo, out, MX, QD, ID);
}